// Round 3
// baseline (347.398 us; speedup 1.0000x reference)
//
#include <hip/hip_runtime.h>
#include <hip/hip_bf16.h>

// RecursiveNN forest bottom-up pass.
// Inputs fp32, OUTPUT fp32 (reference dtype). Internal: split-bf16 MFMA
// (W = Wh + Wl, level-0 leaves split hi/lo) with fp32 accumulate; bf16
// intermediates (one quantization per level handoff).
// Each level: X_l = relu( reshape(X_{l-1}, [M,256]) @ W^T ),  proj = X_l @ P^T + bP.

typedef __bf16 bf16_t;
typedef __bf16 bf16x8 __attribute__((ext_vector_type(8)));
typedef float f32x4 __attribute__((ext_vector_type(4)));

#define BM 128
#define BK 32

// One-shot: split W [128,256] fp32 into bf16 hi + lo planes in workspace.
__global__ void prep_kernel(const float* __restrict__ W,
                            bf16_t* __restrict__ Wh, bf16_t* __restrict__ Wl) {
    const int i = blockIdx.x * 256 + threadIdx.x;     // 128 blocks
    if (i < 128 * 256) {
        const float w = W[i];
        const bf16_t h = (bf16_t)w;
        Wh[i] = h;
        Wl[i] = (bf16_t)(w - (float)h);
    }
}

template<int LVL0>
__global__ __launch_bounds__(256, 2)
void rnn_level_kernel(const void* __restrict__ Ain,    // [M,256] fp32 (lvl0) or bf16
                      const bf16_t* __restrict__ Wh_g, // [128,256] bf16 hi
                      const bf16_t* __restrict__ Wl_g, // [128,256] bf16 lo
                      const float* __restrict__ bW,    // [128] fp32
                      const float* __restrict__ P,     // [5,128] fp32
                      const float* __restrict__ bP,    // [5] fp32
                      bf16_t* __restrict__ Hout,       // [M,128] bf16 next-level input
                      float* __restrict__ Pout)        // [M,5] fp32 projections
{
    // K-phase layout: Ah[128*32] | Al[128*32] | Bh[128*32] | Bl[128*32]  (32 KB)
    // Epilogue overlay: Hs[128][136] bf16 (34816 B) — aliases K-phase tiles.
    __shared__ __align__(16) char smem[34816];
    __shared__ float Ps[5 * 128];                      // 2.5 KB, fp32 P copy

    bf16_t* const Ah = (bf16_t*)smem;
    bf16_t* const Al = Ah + 4096;
    bf16_t* const Bh = Ah + 8192;
    bf16_t* const Bl = Ah + 12288;

    const int tid   = threadIdx.x;
    const int wave  = tid >> 6;
    const int lane  = tid & 63;
    const int wm    = wave & 1;
    const int wn    = wave >> 1;
    const int mlane = lane & 15;
    const int q     = lane >> 4;
    const size_t m0 = (size_t)blockIdx.x * BM;

    // Stage fp32 P once (640 floats = 160 float4)
    if (tid < 160)
        ((float4*)Ps)[tid] = ((const float4*)P)[tid];

    f32x4 acc[4][4] = {};

    for (int k0 = 0; k0 < 256; k0 += BK) {
        if (k0) __syncthreads();                       // prev iter frag reads done
        // ---- global -> LDS staging ----
        if (LVL0) {
            const float* Af = (const float*)Ain;
            #pragma unroll
            for (int j = 0; j < 4; ++j) {
                const int idx  = tid + j * 256;        // 1024 float4 chunks
                const int row  = idx >> 3;
                const int coff = (idx & 7) << 2;
                const float4 v = *(const float4*)&Af[(m0 + row) * 256 + k0 + coff];
                bf16_t hi[4], lo[4];
                hi[0] = (bf16_t)v.x; lo[0] = (bf16_t)(v.x - (float)hi[0]);
                hi[1] = (bf16_t)v.y; lo[1] = (bf16_t)(v.y - (float)hi[1]);
                hi[2] = (bf16_t)v.z; lo[2] = (bf16_t)(v.z - (float)hi[2]);
                hi[3] = (bf16_t)v.w; lo[3] = (bf16_t)(v.w - (float)hi[3]);
                *(uint2*)&Ah[row * BK + coff] = *(const uint2*)hi;
                *(uint2*)&Al[row * BK + coff] = *(const uint2*)lo;
            }
        } else {
            const bf16_t* Ab = (const bf16_t*)Ain;
            #pragma unroll
            for (int j = 0; j < 2; ++j) {
                const int idx  = tid + j * 256;        // 512 x 16B chunks
                const int row  = idx >> 2;
                const int koff = (idx & 3) << 3;
                *(uint4*)&Ah[row * BK + koff] =
                    *(const uint4*)&Ab[(m0 + row) * 256 + k0 + koff];
            }
        }
        #pragma unroll
        for (int j = 0; j < 2; ++j) {
            const int idx  = tid + j * 256;
            const int row  = idx >> 2;
            const int koff = (idx & 3) << 3;
            *(uint4*)&Bh[row * BK + koff] = *(const uint4*)&Wh_g[row * 256 + k0 + koff];
            *(uint4*)&Bl[row * BK + koff] = *(const uint4*)&Wl_g[row * 256 + k0 + koff];
        }
        __syncthreads();

        // ---- LDS -> frags, MFMA ----
        bf16x8 ah[4], al[4], bh[4], bl[4];
        #pragma unroll
        for (int i = 0; i < 4; ++i) {
            ah[i] = *(const bf16x8*)&Ah[(wm * 64 + i * 16 + mlane) * BK + q * 8];
            if (LVL0)
                al[i] = *(const bf16x8*)&Al[(wm * 64 + i * 16 + mlane) * BK + q * 8];
        }
        #pragma unroll
        for (int j = 0; j < 4; ++j) {
            bh[j] = *(const bf16x8*)&Bh[(wn * 64 + j * 16 + mlane) * BK + q * 8];
            bl[j] = *(const bf16x8*)&Bl[(wn * 64 + j * 16 + mlane) * BK + q * 8];
        }
        #pragma unroll
        for (int i = 0; i < 4; ++i)
            #pragma unroll
            for (int j = 0; j < 4; ++j) {
                acc[i][j] = __builtin_amdgcn_mfma_f32_16x16x32_bf16(ah[i], bh[j], acc[i][j], 0, 0, 0);
                acc[i][j] = __builtin_amdgcn_mfma_f32_16x16x32_bf16(ah[i], bl[j], acc[i][j], 0, 0, 0);
                if (LVL0)
                    acc[i][j] = __builtin_amdgcn_mfma_f32_16x16x32_bf16(al[i], bh[j], acc[i][j], 0, 0, 0);
            }
    }

    __syncthreads();                                   // frag reads done; Hs may overwrite

    // ---- epilogue: bias + relu -> Hs (bf16, stride 136 for 16B-aligned rows) ----
    bf16_t* const Hs = (bf16_t*)smem;
    #pragma unroll
    for (int j = 0; j < 4; ++j) {
        const int n = wn * 64 + j * 16 + mlane;
        const float bwv = bW[n];
        #pragma unroll
        for (int i = 0; i < 4; ++i) {
            #pragma unroll
            for (int r = 0; r < 4; ++r) {
                const int lm = wm * 64 + i * 16 + q * 4 + r;
                float v = acc[i][j][r] + bwv;
                v = v > 0.0f ? v : 0.0f;
                Hs[lm * 136 + n] = (bf16_t)v;
            }
        }
    }
    __syncthreads();

    // ---- vectorized Hout store from Hs: 2048 x 16B chunks, 8 per thread ----
    #pragma unroll
    for (int t = 0; t < 8; ++t) {
        const int c   = tid + t * 256;
        const int row = c >> 4;
        const int cc  = (c & 15) << 3;
        *(uint4*)&Hout[(m0 + row) * 128 + cc] = *(const uint4*)&Hs[row * 136 + cc];
    }

    // ---- fused projection (fp32 P), fp32 output ----
    if (tid < 128) {
        float s[5];
        #pragma unroll
        for (int c = 0; c < 5; ++c) s[c] = bP[c];
        #pragma unroll
        for (int kb = 0; kb < 16; ++kb) {
            const bf16x8 hv = *(const bf16x8*)&Hs[tid * 136 + kb * 8];
            #pragma unroll
            for (int c = 0; c < 5; ++c) {
                #pragma unroll
                for (int e = 0; e < 8; ++e)
                    s[c] += (float)hv[e] * Ps[c * 128 + kb * 8 + e];
            }
        }
        #pragma unroll
        for (int c = 0; c < 5; ++c)
            Pout[(m0 + tid) * 5 + c] = s[c];
    }
}

extern "C" void kernel_launch(void* const* d_in, const int* in_sizes, int n_in,
                              void* d_out, int out_size, void* d_ws, size_t ws_size,
                              hipStream_t stream) {
    const float* leaves = (const float*)d_in[0];   // [256,1024,128] fp32
    const float* W      = (const float*)d_in[1];   // [128,256] fp32
    const float* bW     = (const float*)d_in[2];   // [128] fp32
    const float* P      = (const float*)d_in[3];   // [5,128] fp32
    const float* bP     = (const float*)d_in[4];   // [5] fp32
    float* out = (float*)d_out;                    // [256*1023, 5] fp32

    // ws (bf16 elems): Wh 32768 | Wl 32768 | buf0 16.78M | buf1 8.39M  (~50.4 MB)
    bf16_t* Wh   = (bf16_t*)d_ws;
    bf16_t* Wl   = Wh + 32768;
    bf16_t* buf0 = Wh + 65536;
    bf16_t* buf1 = buf0 + (size_t)131072 * 128;

    prep_kernel<<<dim3(128), dim3(256), 0, stream>>>(W, Wh, Wl);

    const void* src = (const void*)leaves;
    int n = 1024;
    size_t out_off = 0;
    int lvl = 0;
    while (n > 1) {
        const int M = 256 * (n >> 1);
        bf16_t* dst = (lvl & 1) ? buf1 : buf0;
        if (lvl == 0) {
            rnn_level_kernel<1><<<dim3(M / BM), dim3(256), 0, stream>>>(
                src, Wh, Wl, bW, P, bP, dst, out + out_off * 5);
        } else {
            rnn_level_kernel<0><<<dim3(M / BM), dim3(256), 0, stream>>>(
                src, Wh, Wl, bW, P, bP, dst, out + out_off * 5);
        }
        out_off += (size_t)M;
        src = (const void*)dst;
        n >>= 1;
        ++lvl;
    }
}

// Round 4
// 321.754 us; speedup vs baseline: 1.0797x; 1.0797x over previous
//
#include <hip/hip_runtime.h>
#include <hip/hip_bf16.h>

// RecursiveNN forest, fused: each block owns a 256-leaf quarter-tree and runs
// all 8 sub-levels LDS-resident (in-place frontier halving). W is held in
// registers as bf16 hi/lo fragments (split-bf16 MFMA, fp32 accumulate).
// Intermediates: bf16 in LDS only. Second tiny kernel does the top 2 levels
// (3 nodes/tree) in fp32 from a 256 KB quarter-root scratch.
// HBM traffic: 134 MB leaves in + 5.5 MB out — no intermediate round-trips.

typedef __bf16 bf16_t;
typedef __bf16 bf16x8 __attribute__((ext_vector_type(8)));
typedef float f32x4 __attribute__((ext_vector_type(4)));

#define HSTRIDE 136   // bf16 elems per H-row slot: 272 B rows, 16B-aligned

static __device__ __forceinline__ f32x4 mfma16(bf16x8 a, bf16x8 b, f32x4 c) {
    return __builtin_amdgcn_mfma_f32_16x16x32_bf16(a, b, c, 0, 0, 0);
}

__global__ __launch_bounds__(256, 2)
void rnn_subtree_kernel(const float* __restrict__ leaves,
                        const float* __restrict__ W,
                        const float* __restrict__ bW,
                        const float* __restrict__ P,
                        const float* __restrict__ bP,
                        bf16_t* __restrict__ Q,     // [1024][128] quarter roots
                        float* __restrict__ out)
{
    __shared__ bf16_t Hbuf[128 * HSTRIDE];          // 34816 B, in-place frontier
    __shared__ bf16_t Stg[2][32 * HSTRIDE];         // 17408 B, leaf staging dbuf
    __shared__ float  Ps[5 * 128];                  // 2560 B
    __shared__ float  bPs[5];

    const int tid   = threadIdx.x;
    const int wave  = tid >> 6;
    const int lane  = tid & 63;
    const int mlane = lane & 15;
    const int q     = lane >> 4;
    const int tree  = blockIdx.x >> 2;
    const int qq    = blockIdx.x & 3;
    const float* leafbase = leaves + (size_t)blockIdx.x * 32768;  // 256 leaves * 128

    if (tid < 160) ((float4*)Ps)[tid] = ((const float4*)P)[tid];
    if (tid < 5)   bPs[tid] = bP[tid];

    // ---- W fragments (hi+lo) in registers. Wave owns cols [32w, 32w+32). ----
    // b-frag (gemm_bt): lane holds W[col = ntile*16 + mlane][k0 + q*8 + e]
    bf16x8 wh[2][8], wl[2][8];
    float bwv[2];
    #pragma unroll
    for (int n = 0; n < 2; ++n) {
        const int col = wave * 32 + n * 16 + mlane;
        bwv[n] = bW[col];
        const float* wr = W + col * 256;
        #pragma unroll
        for (int k = 0; k < 8; ++k) {
            #pragma unroll
            for (int e = 0; e < 8; ++e) {
                const float w  = wr[k * 32 + q * 8 + e];
                const bf16_t h = (bf16_t)w;
                wh[n][k][e] = h;
                wl[n][k][e] = (bf16_t)(w - (float)h);
            }
        }
    }

    // stage a prefetched 16-pair-row leaf chunk (32 leaf rows x 128 fp32) as bf16
    auto store_stage = [&](int buf, const float4* pf) {
        #pragma unroll
        for (int r = 0; r < 4; ++r) {
            const int idx = tid + r * 256;          // 1024 float4 chunks
            const int row = idx >> 5;               // 32 float4 per leaf row
            const int c4  = idx & 31;
            bf16_t t4[4] = {(bf16_t)pf[r].x, (bf16_t)pf[r].y,
                            (bf16_t)pf[r].z, (bf16_t)pf[r].w};
            *(uint2*)&Stg[buf][row * HSTRIDE + c4 * 4] = *(const uint2*)t4;
        }
    };

    // per-level projection: M valid rows in Hbuf -> out rows off + tree*4M + qq*M + t
    auto proj = [&](int M, int off) {
        if (tid < M) {
            float s0 = bPs[0], s1 = bPs[1], s2 = bPs[2], s3 = bPs[3], s4 = bPs[4];
            #pragma unroll
            for (int kb = 0; kb < 16; ++kb) {
                const bf16x8 hv = *(const bf16x8*)&Hbuf[tid * HSTRIDE + kb * 8];
                #pragma unroll
                for (int e = 0; e < 8; ++e) {
                    const float h = (float)hv[e];
                    const int  kk = kb * 8 + e;
                    s0 += h * Ps[0 * 128 + kk];
                    s1 += h * Ps[1 * 128 + kk];
                    s2 += h * Ps[2 * 128 + kk];
                    s3 += h * Ps[3 * 128 + kk];
                    s4 += h * Ps[4 * 128 + kk];
                }
            }
            float* po = out + ((size_t)off + (size_t)tree * (M * 4) + qq * M + tid) * 5;
            po[0] = s0; po[1] = s1; po[2] = s2; po[3] = s3; po[4] = s4;
        }
    };

    // ---- phase 1: level 1 (128 pair-rows, 8 chunks) from streamed leaves ----
    float4 pf[4];
    #pragma unroll
    for (int r = 0; r < 4; ++r) pf[r] = ((const float4*)leafbase)[tid + r * 256];
    store_stage(0, pf);

    for (int c = 0; c < 8; ++c) {
        __syncthreads();                            // Stg[c&1] writes visible
        if (c < 7) {
            #pragma unroll
            for (int r = 0; r < 4; ++r)
                pf[r] = ((const float4*)leafbase)[(c + 1) * 1024 + tid + r * 256];
        }
        bf16x8 af[8];
        const bf16_t* sb = Stg[c & 1];
        #pragma unroll
        for (int k = 0; k < 8; ++k) {
            const int off  = k * 64 + q * 16;       // byte offset in 512B pair-row
            const int trow = off >> 8;
            const int ce   = (off & 255) >> 1;      // bf16-elem offset within row
            af[k] = *(const bf16x8*)&sb[(2 * mlane + trow) * HSTRIDE + ce];
        }
        f32x4 acc[2] = {};
        #pragma unroll
        for (int k = 0; k < 8; ++k) {
            acc[0] = mfma16(af[k], wh[0][k], acc[0]);
            acc[1] = mfma16(af[k], wh[1][k], acc[1]);
            acc[0] = mfma16(af[k], wl[0][k], acc[0]);
            acc[1] = mfma16(af[k], wl[1][k], acc[1]);
        }
        if (c < 7) store_stage((c + 1) & 1, pf);
        #pragma unroll
        for (int n = 0; n < 2; ++n)
            #pragma unroll
            for (int r = 0; r < 4; ++r) {
                float v = acc[n][r] + bwv[n];
                v = fmaxf(v, 0.f);
                Hbuf[(c * 16 + q * 4 + r) * HSTRIDE + wave * 32 + n * 16 + mlane] = (bf16_t)v;
            }
    }

    __syncthreads();
    proj(128, 0);                                   // level 1, off=0

    // ---- phases 2..8: LDS-resident in-place levels ----
    int Mprev = 128;
    #pragma unroll 1
    for (int j = 2; j <= 8; ++j) {
        const int Mnew   = Mprev >> 1;
        const int chunks = (Mnew + 15) >> 4;
        __syncthreads();                            // proj reads done before overwrite
        for (int c = 0; c < chunks; ++c) {
            bf16x8 af[8];
            #pragma unroll
            for (int k = 0; k < 8; ++k) {
                const int off  = k * 64 + q * 16;
                const int trow = off >> 8;
                const int ce   = (off & 255) >> 1;
                af[k] = *(const bf16x8*)&Hbuf[(32 * c + 2 * mlane + trow) * HSTRIDE + ce];
            }
            __syncthreads();                        // all reads done before any write
            f32x4 acc[2] = {};
            #pragma unroll
            for (int k = 0; k < 8; ++k) {
                acc[0] = mfma16(af[k], wh[0][k], acc[0]);
                acc[1] = mfma16(af[k], wh[1][k], acc[1]);
                acc[0] = mfma16(af[k], wl[0][k], acc[0]);
                acc[1] = mfma16(af[k], wl[1][k], acc[1]);
            }
            #pragma unroll
            for (int n = 0; n < 2; ++n)
                #pragma unroll
                for (int r = 0; r < 4; ++r) {
                    float v = acc[n][r] + bwv[n];
                    v = fmaxf(v, 0.f);
                    Hbuf[(c * 16 + q * 4 + r) * HSTRIDE + wave * 32 + n * 16 + mlane] = (bf16_t)v;
                }
            __syncthreads();
        }
        proj(Mnew, 256 * (1024 - (2048 >> j)));
        Mprev = Mnew;
    }

    // quarter root (Hbuf row 0) -> global scratch
    if (tid < 16)
        *(uint4*)&Q[(size_t)blockIdx.x * 128 + tid * 8] = *(const uint4*)&Hbuf[tid * 8];
}

// Top 2 levels (2 nodes + root per tree), pure fp32 from bf16 quarter roots.
__global__ __launch_bounds__(128, 4)
void rnn_top_kernel(const bf16_t* __restrict__ Q,
                    const float* __restrict__ W,
                    const float* __restrict__ bW,
                    const float* __restrict__ P,
                    const float* __restrict__ bP,
                    float* __restrict__ out)
{
    __shared__ float qs[512];
    __shared__ float hs[384];
    const int t    = threadIdx.x;
    const int tree = blockIdx.x;

    #pragma unroll
    for (int i = 0; i < 4; ++i)
        qs[t + i * 128] = (float)Q[(size_t)tree * 512 + t + i * 128];
    __syncthreads();

    const float* wr = W + t * 256;
    float s0 = bW[t], s1 = s0;
    for (int k = 0; k < 256; k += 4) {
        const float4 wv = *(const float4*)(wr + k);
        s0 += wv.x * qs[k]     + wv.y * qs[k + 1]     + wv.z * qs[k + 2]     + wv.w * qs[k + 3];
        s1 += wv.x * qs[256+k] + wv.y * qs[256+k + 1] + wv.z * qs[256+k + 2] + wv.w * qs[256+k + 3];
    }
    hs[t]       = fmaxf(s0, 0.f);
    hs[128 + t] = fmaxf(s1, 0.f);
    __syncthreads();

    float s2 = bW[t];
    for (int k = 0; k < 256; k += 4) {
        const float4 wv = *(const float4*)(wr + k);
        s2 += wv.x * hs[k] + wv.y * hs[k + 1] + wv.z * hs[k + 2] + wv.w * hs[k + 3];
    }
    hs[256 + t] = fmaxf(s2, 0.f);
    __syncthreads();

    if (t < 15) {
        const int node = t / 5, c = t % 5;
        float s = bP[c];
        for (int k = 0; k < 128; ++k) s += hs[node * 128 + k] * P[c * 128 + k];
        const size_t row = (node < 2) ? (261120 + (size_t)tree * 2 + node)
                                      : (261632 + (size_t)tree);
        out[row * 5 + c] = s;
    }
}

extern "C" void kernel_launch(void* const* d_in, const int* in_sizes, int n_in,
                              void* d_out, int out_size, void* d_ws, size_t ws_size,
                              hipStream_t stream) {
    const float* leaves = (const float*)d_in[0];   // [256,1024,128] fp32
    const float* W      = (const float*)d_in[1];   // [128,256] fp32
    const float* bW     = (const float*)d_in[2];   // [128] fp32
    const float* P      = (const float*)d_in[3];   // [5,128] fp32
    const float* bP     = (const float*)d_in[4];   // [5] fp32
    float* out = (float*)d_out;                    // [256*1023, 5] fp32

    bf16_t* Q = (bf16_t*)d_ws;                     // [1024][128] quarter roots, 256 KB

    rnn_subtree_kernel<<<dim3(1024), dim3(256), 0, stream>>>(leaves, W, bW, P, bP, Q, out);
    rnn_top_kernel<<<dim3(256), dim3(128), 0, stream>>>(Q, W, bW, P, bP, out);
}

// Round 5
// 281.902 us; speedup vs baseline: 1.2323x; 1.1414x over previous
//
#include <hip/hip_runtime.h>
#include <hip/hip_bf16.h>
#include <hip/hip_fp16.h>

// RecursiveNN forest bottom-up pass, fp32 in / fp32 out.
// Internal: fp16 MFMA (values are Glorot-scaled, |x| << 6e4 -> fp16-safe),
// fp32 accumulate, fp16 level handoffs (2^-11 rounding).
// K1: level 1 streaming GEMM over 134 MB leaves (BW-bound).
// K2: levels 2..8 LDS-resident per 128-row quarter-tree (in-place halving).
// K3: top 2 levels (3 nodes/tree) in fp32.

typedef _Float16 f16_t;
typedef _Float16 f16x4 __attribute__((ext_vector_type(4)));
typedef _Float16 f16x8 __attribute__((ext_vector_type(8)));
typedef float f32x4 __attribute__((ext_vector_type(4)));

#define HSTRIDE 136   // f16 elems per row slot: 272 B, 16B-aligned

static __device__ __forceinline__ f32x4 mfma16(f16x8 a, f16x8 b, f32x4 c) {
    return __builtin_amdgcn_mfma_f32_16x16x32_f16(a, b, c, 0, 0, 0);
}

// One-shot: W [128,256] fp32 -> fp16 in workspace.
__global__ void prep_kernel(const float* __restrict__ W, f16_t* __restrict__ Wh) {
    const int i = blockIdx.x * 256 + threadIdx.x;   // grid 128
    Wh[i] = (f16_t)W[i];
}

// ---------------- K1: level 1 ----------------
// Block = 128 pair-rows (256 leaf rows, 128 KB fp32). Wave w owns cols [32w,32w+32).
__global__ __launch_bounds__(256, 2)
void level1_kernel(const float* __restrict__ leaves,
                   const f16_t* __restrict__ Wh,
                   const float* __restrict__ bW,
                   const float* __restrict__ P,
                   const float* __restrict__ bP,
                   f16_t* __restrict__ H1,      // [131072,128] f16
                   float* __restrict__ out)
{
    __shared__ f16_t Stg[2][32 * HSTRIDE];       // 17408 B leaf staging dbuf
    __shared__ f16_t Hs[16 * HSTRIDE];           // 4352 B current H chunk
    __shared__ float Ps[640];
    __shared__ float bPs[5];

    const int tid   = threadIdx.x;
    const int wave  = tid >> 6;
    const int lane  = tid & 63;
    const int mlane = lane & 15;
    const int q     = lane >> 4;
    const size_t m0 = (size_t)blockIdx.x * 128;  // global pair-row base
    const float* leafbase = leaves + (size_t)blockIdx.x * 32768;

    if (tid < 160) ((float4*)Ps)[tid] = ((const float4*)P)[tid];
    if (tid < 5)   bPs[tid] = bP[tid];

    // W b-frags (gemm_bt, verified): lane holds W[col][k*32 + q*8 + e]
    f16x8 wh[2][8];
    float bwv[2];
    #pragma unroll
    for (int n = 0; n < 2; ++n) {
        const int col = wave * 32 + n * 16 + mlane;
        bwv[n] = bW[col];
        #pragma unroll
        for (int k = 0; k < 8; ++k)
            wh[n][k] = *(const f16x8*)&Wh[col * 256 + k * 32 + q * 8];
    }

    auto store_stage = [&](int buf, const float4* pf) {
        #pragma unroll
        for (int r = 0; r < 4; ++r) {
            const int idx = tid + r * 256;       // 1024 float4 chunks = 32 leaf rows
            const int row = idx >> 5;
            const int c4  = idx & 31;
            f16x4 t4 = { (f16_t)pf[r].x, (f16_t)pf[r].y, (f16_t)pf[r].z, (f16_t)pf[r].w };
            *(f16x4*)&Stg[buf][row * HSTRIDE + c4 * 4] = t4;
        }
    };

    float4 pf[4];
    #pragma unroll
    for (int r = 0; r < 4; ++r) pf[r] = ((const float4*)leafbase)[tid + r * 256];
    store_stage(0, pf);

    for (int c = 0; c < 8; ++c) {
        __syncthreads();                         // Stg[c&1] visible; prev Hs consumed
        if (c < 7) {
            #pragma unroll
            for (int r = 0; r < 4; ++r)
                pf[r] = ((const float4*)leafbase)[(c + 1) * 1024 + tid + r * 256];
        }
        // A-frags from pair-rows (verified pattern)
        f16x8 af[8];
        const f16_t* sb = Stg[c & 1];
        #pragma unroll
        for (int k = 0; k < 8; ++k) {
            const int off  = k * 64 + q * 16;    // byte offset in 512B pair-row
            const int trow = off >> 8;
            const int ce   = (off & 255) >> 1;
            af[k] = *(const f16x8*)&sb[(2 * mlane + trow) * HSTRIDE + ce];
        }
        f32x4 acc0 = {}, acc1 = {};
        #pragma unroll
        for (int k = 0; k < 8; ++k) {
            acc0 = mfma16(af[k], wh[0][k], acc0);
            acc1 = mfma16(af[k], wh[1][k], acc1);
        }
        if (c < 7) store_stage((c + 1) & 1, pf);

        // bias + relu -> Hs (C-layout: col=lane&15, row=q*4+r — verified)
        #pragma unroll
        for (int r = 0; r < 4; ++r) {
            float v0 = fmaxf(acc0[r] + bwv[0], 0.f);
            float v1 = fmaxf(acc1[r] + bwv[1], 0.f);
            Hs[(q * 4 + r) * HSTRIDE + wave * 32 + mlane]      = (f16_t)v0;
            Hs[(q * 4 + r) * HSTRIDE + wave * 32 + 16 + mlane] = (f16_t)v1;
        }
        __syncthreads();                         // Hs complete

        // vectorized H1 store: 256 x uint4 (16 rows x 128 f16)
        {
            const int row = tid >> 4;
            const int c8  = (tid & 15) * 8;
            *(uint4*)&H1[(m0 + c * 16 + row) * 128 + c8] =
                *(const uint4*)&Hs[row * HSTRIDE + c8];
        }
        // proj: 80 threads, one (row, class) dot each
        if (tid < 80) {
            const int row = tid / 5;
            const int cc  = tid - row * 5;
            float s = bPs[cc];
            #pragma unroll
            for (int kb = 0; kb < 16; ++kb) {
                const f16x8  hv = *(const f16x8*)&Hs[row * HSTRIDE + kb * 8];
                const float4 p0 = *(const float4*)&Ps[cc * 128 + kb * 8];
                const float4 p1 = *(const float4*)&Ps[cc * 128 + kb * 8 + 4];
                s += (float)hv[0] * p0.x + (float)hv[1] * p0.y
                   + (float)hv[2] * p0.z + (float)hv[3] * p0.w
                   + (float)hv[4] * p1.x + (float)hv[5] * p1.y
                   + (float)hv[6] * p1.z + (float)hv[7] * p1.w;
            }
            out[(m0 + c * 16 + row) * 5 + cc] = s;
        }
    }
}

// ---------------- K2: levels 2..8 ----------------
// Block = one 128-row quarter of a tree's level-1 frontier; in-place LDS halving.
__global__ __launch_bounds__(256, 2)
void tree_kernel(const f16_t* __restrict__ H1,
                 const f16_t* __restrict__ Wh,
                 const float* __restrict__ bW,
                 const float* __restrict__ P,
                 const float* __restrict__ bP,
                 f16_t* __restrict__ Q,          // [1024,128] quarter roots
                 float* __restrict__ out)
{
    __shared__ f16_t Hbuf[128 * HSTRIDE];        // 34816 B
    __shared__ float Ps[640];
    __shared__ float bPs[5];

    const int tid   = threadIdx.x;
    const int wave  = tid >> 6;
    const int lane  = tid & 63;
    const int mlane = lane & 15;
    const int q     = lane >> 4;
    const int tree  = blockIdx.x >> 2;
    const int qq    = blockIdx.x & 3;

    if (tid < 160) ((float4*)Ps)[tid] = ((const float4*)P)[tid];
    if (tid < 5)   bPs[tid] = bP[tid];

    f16x8 wh[2][8];
    float bwv[2];
    #pragma unroll
    for (int n = 0; n < 2; ++n) {
        const int col = wave * 32 + n * 16 + mlane;
        bwv[n] = bW[col];
        #pragma unroll
        for (int k = 0; k < 8; ++k)
            wh[n][k] = *(const f16x8*)&Wh[col * 256 + k * 32 + q * 8];
    }

    // load this block's 128 H1 rows (32 KB, coalesced)
    {
        const f16_t* src = H1 + (size_t)blockIdx.x * 16384;
        #pragma unroll
        for (int r = 0; r < 8; ++r) {
            const int idx = tid + r * 256;
            const int row = idx >> 4;
            const int c8  = (idx & 15) * 8;
            *(uint4*)&Hbuf[row * HSTRIDE + c8] = *(const uint4*)&src[row * 128 + c8];
        }
    }
    __syncthreads();

    int Mprev = 128;
    #pragma unroll 1
    for (int j = 2; j <= 8; ++j) {
        const int Mnew   = Mprev >> 1;
        const int chunks = (Mnew + 15) >> 4;
        const int off_j  = 256 * (1024 - (2048 >> j));
        for (int c = 0; c < chunks; ++c) {
            f16x8 af[8];
            #pragma unroll
            for (int k = 0; k < 8; ++k) {
                const int off  = k * 64 + q * 16;
                const int trow = off >> 8;
                const int ce   = (off & 255) >> 1;
                af[k] = *(const f16x8*)&Hbuf[(32 * c + 2 * mlane + trow) * HSTRIDE + ce];
            }
            __syncthreads();                     // all reads done before writes
            f32x4 acc0 = {}, acc1 = {};
            #pragma unroll
            for (int k = 0; k < 8; ++k) {
                acc0 = mfma16(af[k], wh[0][k], acc0);
                acc1 = mfma16(af[k], wh[1][k], acc1);
            }
            #pragma unroll
            for (int r = 0; r < 4; ++r) {
                float v0 = fmaxf(acc0[r] + bwv[0], 0.f);
                float v1 = fmaxf(acc1[r] + bwv[1], 0.f);
                Hbuf[(c * 16 + q * 4 + r) * HSTRIDE + wave * 32 + mlane]      = (f16_t)v0;
                Hbuf[(c * 16 + q * 4 + r) * HSTRIDE + wave * 32 + 16 + mlane] = (f16_t)v1;
            }
            __syncthreads();                     // writes visible for proj / next reads

            const int valid = (Mnew - c * 16 < 16) ? (Mnew - c * 16) : 16;
            if (tid < valid * 5) {
                const int row = tid / 5;
                const int cc  = tid - row * 5;
                float s = bPs[cc];
                #pragma unroll
                for (int kb = 0; kb < 16; ++kb) {
                    const f16x8  hv = *(const f16x8*)&Hbuf[(c * 16 + row) * HSTRIDE + kb * 8];
                    const float4 p0 = *(const float4*)&Ps[cc * 128 + kb * 8];
                    const float4 p1 = *(const float4*)&Ps[cc * 128 + kb * 8 + 4];
                    s += (float)hv[0] * p0.x + (float)hv[1] * p0.y
                       + (float)hv[2] * p0.z + (float)hv[3] * p0.w
                       + (float)hv[4] * p1.x + (float)hv[5] * p1.y
                       + (float)hv[6] * p1.z + (float)hv[7] * p1.w;
                }
                out[((size_t)off_j + (size_t)tree * (Mnew * 4) + qq * Mnew + c * 16 + row) * 5 + cc] = s;
            }
        }
        Mprev = Mnew;
    }

    if (tid < 16)
        *(uint4*)&Q[(size_t)blockIdx.x * 128 + tid * 8] = *(const uint4*)&Hbuf[tid * 8];
}

// ---------------- K3: top 2 levels, fp32 (verified round 4) ----------------
__global__ __launch_bounds__(128, 4)
void rnn_top_kernel(const f16_t* __restrict__ Q,
                    const float* __restrict__ W,
                    const float* __restrict__ bW,
                    const float* __restrict__ P,
                    const float* __restrict__ bP,
                    float* __restrict__ out)
{
    __shared__ float qs[512];
    __shared__ float hs[384];
    const int t    = threadIdx.x;
    const int tree = blockIdx.x;

    #pragma unroll
    for (int i = 0; i < 4; ++i)
        qs[t + i * 128] = (float)Q[(size_t)tree * 512 + t + i * 128];
    __syncthreads();

    const float* wr = W + t * 256;
    float s0 = bW[t], s1 = s0;
    for (int k = 0; k < 256; k += 4) {
        const float4 wv = *(const float4*)(wr + k);
        s0 += wv.x * qs[k]     + wv.y * qs[k + 1]     + wv.z * qs[k + 2]     + wv.w * qs[k + 3];
        s1 += wv.x * qs[256+k] + wv.y * qs[256+k + 1] + wv.z * qs[256+k + 2] + wv.w * qs[256+k + 3];
    }
    hs[t]       = fmaxf(s0, 0.f);
    hs[128 + t] = fmaxf(s1, 0.f);
    __syncthreads();

    float s2 = bW[t];
    for (int k = 0; k < 256; k += 4) {
        const float4 wv = *(const float4*)(wr + k);
        s2 += wv.x * hs[k] + wv.y * hs[k + 1] + wv.z * hs[k + 2] + wv.w * hs[k + 3];
    }
    hs[256 + t] = fmaxf(s2, 0.f);
    __syncthreads();

    if (t < 15) {
        const int node = t / 5, c = t % 5;
        float s = bP[c];
        for (int k = 0; k < 128; ++k) s += hs[node * 128 + k] * P[c * 128 + k];
        const size_t row = (node < 2) ? (261120 + (size_t)tree * 2 + node)
                                      : (261632 + (size_t)tree);
        out[row * 5 + c] = s;
    }
}

extern "C" void kernel_launch(void* const* d_in, const int* in_sizes, int n_in,
                              void* d_out, int out_size, void* d_ws, size_t ws_size,
                              hipStream_t stream) {
    const float* leaves = (const float*)d_in[0];   // [256,1024,128] fp32
    const float* W      = (const float*)d_in[1];   // [128,256] fp32
    const float* bW     = (const float*)d_in[2];   // [128] fp32
    const float* P      = (const float*)d_in[3];   // [5,128] fp32
    const float* bP     = (const float*)d_in[4];   // [5] fp32
    float* out = (float*)d_out;                    // [256*1023, 5] fp32

    // ws layout (f16 elems): Wh 32768 | Q 131072 | H1 16777216  (~34 MB)
    f16_t* Wh = (f16_t*)d_ws;
    f16_t* Q  = Wh + 32768;
    f16_t* H1 = Wh + 32768 + 131072;

    prep_kernel<<<dim3(128), dim3(256), 0, stream>>>(W, Wh);
    level1_kernel<<<dim3(1024), dim3(256), 0, stream>>>(leaves, Wh, bW, P, bP, H1, out);
    tree_kernel<<<dim3(1024), dim3(256), 0, stream>>>(H1, Wh, bW, P, bP, Q, out);
    rnn_top_kernel<<<dim3(256), dim3(128), 0, stream>>>(Q, W, bW, P, bP, out);
}